// Round 3
// baseline (270.925 us; speedup 1.0000x reference)
//
#include <hip/hip_runtime.h>
#include <hip/hip_bf16.h>

// out = kipf - lbda[:,None] * input
// N_NODES=100000, N_FEATURES=256, f32. Pure elementwise streaming, HBM-bound.
// Persistent grid-stride waves, 4x float4 per iteration for memory-level
// parallelism, nontemporal stores for the write-only output.
// Uses clang ext_vector_type (not HIP float4) so __builtin_nontemporal_store
// accepts the pointer type.

typedef float v4f __attribute__((ext_vector_type(4)));

#define BLOCK 256
#define GRID  2048   // 8 blocks/CU * 256 CUs

__global__ __launch_bounds__(BLOCK) void damping_kernel(
    const v4f* __restrict__ input4,
    const v4f* __restrict__ kipf4,
    const float* __restrict__ lbda,
    v4f* __restrict__ out4,
    int n4)  // total v4f elements = N_NODES * 64 (64 per row)
{
    const int stride = gridDim.x * blockDim.x;
    int i = blockIdx.x * blockDim.x + threadIdx.x;

    // Main loop: 4 elements per iteration, loads batched for ILP.
    for (; i + 3 * stride < n4; i += 4 * stride) {
        const int i0 = i, i1 = i + stride, i2 = i + 2 * stride, i3 = i + 3 * stride;
        v4f a0 = input4[i0];
        v4f a1 = input4[i1];
        v4f a2 = input4[i2];
        v4f a3 = input4[i3];
        v4f k0 = kipf4[i0];
        v4f k1 = kipf4[i1];
        v4f k2 = kipf4[i2];
        v4f k3 = kipf4[i3];
        float l0 = lbda[i0 >> 6];
        float l1 = lbda[i1 >> 6];
        float l2 = lbda[i2 >> 6];
        float l3 = lbda[i3 >> 6];
        v4f o0 = k0 - l0 * a0;
        v4f o1 = k1 - l1 * a1;
        v4f o2 = k2 - l2 * a2;
        v4f o3 = k3 - l3 * a3;
        __builtin_nontemporal_store(o0, &out4[i0]);
        __builtin_nontemporal_store(o1, &out4[i1]);
        __builtin_nontemporal_store(o2, &out4[i2]);
        __builtin_nontemporal_store(o3, &out4[i3]);
    }
    // Tail
    for (; i < n4; i += stride) {
        float l = lbda[i >> 6];
        v4f a = input4[i];
        v4f k = kipf4[i];
        v4f o = k - l * a;
        __builtin_nontemporal_store(o, &out4[i]);
    }
}

extern "C" void kernel_launch(void* const* d_in, const int* in_sizes, int n_in,
                              void* d_out, int out_size, void* d_ws, size_t ws_size,
                              hipStream_t stream) {
    const v4f* input4 = (const v4f*)d_in[0];   // input_term (100000,256) f32
    const v4f* kipf4  = (const v4f*)d_in[1];   // kipf_term  (100000,256) f32
    const float* lbda = (const float*)d_in[2]; // lbda (100000,) f32
    // d_in[3] = spar (scalar, always 1) -- unused
    v4f* out4 = (v4f*)d_out;

    int n4 = out_size / 4;                     // 6,400,000
    damping_kernel<<<GRID, BLOCK, 0, stream>>>(input4, kipf4, lbda, out4, n4);
}

// Round 4
// 248.307 us; speedup vs baseline: 1.0911x; 1.0911x over previous
//
#include <hip/hip_runtime.h>
#include <hip/hip_bf16.h>

// out = kipf - lbda[:,None] * input
// N_NODES=100000, N_FEATURES=256, f32. Elementwise streaming, HBM-bound.
// Flat block-contiguous layout: each block owns a 1024-float4 (16 KB) chunk;
// thread t handles base+t, base+256, base+512, base+768 -> 3 compact HBM
// streams per block, 8 outstanding dwordx4 loads per wave. Plain stores
// (NT stores regressed in R3 when combined with scattered grid-stride; this
// round isolates layout).

typedef float v4f __attribute__((ext_vector_type(4)));

#define BLOCK 256
#define VPT   4   // float4 per thread; chunk = BLOCK*VPT = 1024 float4

__global__ __launch_bounds__(BLOCK) void damping_kernel(
    const v4f* __restrict__ input4,
    const v4f* __restrict__ kipf4,
    const float* __restrict__ lbda,
    v4f* __restrict__ out4,
    int n4)  // total float4 elements = N_NODES * 64
{
    int base = blockIdx.x * (BLOCK * VPT) + threadIdx.x;
    int i0 = base;
    int i1 = base + BLOCK;
    int i2 = base + 2 * BLOCK;
    int i3 = base + 3 * BLOCK;

    if (i3 < n4) {
        // Fast path (always taken for 100000x256: 6.4M = 6250*1024 exactly)
        v4f a0 = input4[i0];
        v4f a1 = input4[i1];
        v4f a2 = input4[i2];
        v4f a3 = input4[i3];
        v4f k0 = kipf4[i0];
        v4f k1 = kipf4[i1];
        v4f k2 = kipf4[i2];
        v4f k3 = kipf4[i3];
        float l0 = lbda[i0 >> 6];
        float l1 = lbda[i1 >> 6];
        float l2 = lbda[i2 >> 6];
        float l3 = lbda[i3 >> 6];
        out4[i0] = k0 - l0 * a0;
        out4[i1] = k1 - l1 * a1;
        out4[i2] = k2 - l2 * a2;
        out4[i3] = k3 - l3 * a3;
    } else {
        #pragma unroll
        for (int k = 0; k < VPT; ++k) {
            int i = base + k * BLOCK;
            if (i < n4) {
                float l = lbda[i >> 6];
                out4[i] = kipf4[i] - l * input4[i];
            }
        }
    }
}

extern "C" void kernel_launch(void* const* d_in, const int* in_sizes, int n_in,
                              void* d_out, int out_size, void* d_ws, size_t ws_size,
                              hipStream_t stream) {
    const v4f* input4 = (const v4f*)d_in[0];   // input_term (100000,256) f32
    const v4f* kipf4  = (const v4f*)d_in[1];   // kipf_term  (100000,256) f32
    const float* lbda = (const float*)d_in[2]; // lbda (100000,) f32
    // d_in[3] = spar (scalar, always 1) -- unused
    v4f* out4 = (v4f*)d_out;

    int n4 = out_size / 4;                               // 6,400,000
    int grid = (n4 + BLOCK * VPT - 1) / (BLOCK * VPT);   // 6250 blocks
    damping_kernel<<<grid, BLOCK, 0, stream>>>(input4, kipf4, lbda, out4, n4);
}

// Round 5
// 247.139 us; speedup vs baseline: 1.0962x; 1.0047x over previous
//
#include <hip/hip_runtime.h>
#include <hip/hip_bf16.h>

// out = kipf - lbda[:,None] * input
// N_NODES=100000, N_FEATURES=256, f32. Elementwise streaming, HBM-bound.
// Round 5: exact R1 structure (1 float4/thread, 25000 blocks -- the best so
// far at 86.6 us) + nontemporal store as the single isolated change.
// Theory: write-allocate of the 102 MB output evicts L3-resident input before
// it's read; nt store preserves input residency -> FETCH_SIZE and dur drop.

typedef float v4f __attribute__((ext_vector_type(4)));

#define BLOCK 256

__global__ __launch_bounds__(BLOCK) void damping_kernel(
    const v4f* __restrict__ input4,
    const v4f* __restrict__ kipf4,
    const float* __restrict__ lbda,
    v4f* __restrict__ out4,
    int n4)  // total float4 elements = N_NODES * 64 (64 per row)
{
    int i = blockIdx.x * blockDim.x + threadIdx.x;
    if (i >= n4) return;
    int row = i >> 6;               // 256 floats = 64 float4 per row
    float l = lbda[row];            // broadcast within row, cache-served
    v4f a = input4[i];
    v4f k = kipf4[i];
    v4f o = k - l * a;
    __builtin_nontemporal_store(o, &out4[i]);
}

extern "C" void kernel_launch(void* const* d_in, const int* in_sizes, int n_in,
                              void* d_out, int out_size, void* d_ws, size_t ws_size,
                              hipStream_t stream) {
    const v4f* input4 = (const v4f*)d_in[0];   // input_term (100000,256) f32
    const v4f* kipf4  = (const v4f*)d_in[1];   // kipf_term  (100000,256) f32
    const float* lbda = (const float*)d_in[2]; // lbda (100000,) f32
    // d_in[3] = spar (scalar, always 1) -- unused
    v4f* out4 = (v4f*)d_out;

    int n4 = out_size / 4;                     // 6,400,000
    int grid = (n4 + BLOCK - 1) / BLOCK;       // 25000 blocks
    damping_kernel<<<grid, BLOCK, 0, stream>>>(input4, kipf4, lbda, out4, n4);
}